// Round 1
// baseline (6988.789 us; speedup 1.0000x reference)
//
#include <hip/hip_runtime.h>
#include <math.h>

// Problem constants
constexpr int B_    = 32;
constexpr int C_IN  = 64;
constexpr int T_    = 256;
constexpr int V_    = 25;
constexpr int C_OUT = 128;
constexpr int H_    = 4;
constexpr int D_    = 32;
constexpr int TVv   = T_ * V_;                 // 6400
constexpr long long TENSOR = (long long)B_ * C_OUT * TVv; // 26,214,400 floats

// ws layout (in floats)
constexpr long long XG_OFF  = 0;
constexpr long long Y_OFF   = XG_OFF + TENSOR;
constexpr long long ACC_OFF = Y_OFF + TENSOR;
constexpr long long WR3_OFF = ACC_OFF + TENSOR;
constexpr long long WR5_OFF = WR3_OFF + 128 * 128 * 3;
constexpr long long WR7_OFF = WR5_OFF + 128 * 128 * 5;
constexpr long long FUSR_OFF = WR7_OFF + 128 * 128 * 7;
constexpr long long RESR_OFF = FUSR_OFF + 384 * 128;
constexpr long long STAT1_OFF = RESR_OFF + 64 * 128;  // mu1[256], rstd1[256]
constexpr long long STAT2_OFF = STAT1_OFF + 512;      // mu2[256], rstd2[256]
constexpr long long STAT3_OFF = STAT2_OFF + 512;      // mu3[256], rstd3[256]

// ---------------- repack kernels ----------------
// conv weight (co, ci, k) -> wr[(ci*K+dt)*128 + co]
__global__ void repack_conv_kernel(const float* __restrict__ w, float* __restrict__ wr, int K) {
    int idx = blockIdx.x * 256 + threadIdx.x;
    int tot = 128 * 128 * K;
    if (idx >= tot) return;
    int co  = idx / (128 * K);
    int rem = idx - co * 128 * K;
    int ci  = rem / K;
    int dt  = rem - ci * K;
    wr[(ci * K + dt) * 128 + co] = w[idx];
}

// w[rows][cols] -> wr[cols][rows]
__global__ void repack_mat_kernel(const float* __restrict__ w, float* __restrict__ wr, int rows, int cols) {
    int idx = blockIdx.x * 256 + threadIdx.x;
    if (idx >= rows * cols) return;
    int r = idx / cols, c = idx - r * cols;
    wr[c * rows + r] = w[idx];
}

// ---------------- GAT kernel ----------------
__global__ __launch_bounds__(256) void gat_kernel(const float* __restrict__ x,
                                                  const float* __restrict__ adj,
                                                  const float* __restrict__ wg,
                                                  const float* __restrict__ ag,
                                                  float* __restrict__ xg) {
    __shared__ float s_x[26 * 64];        // [v][c]
    __shared__ float s_wg[64 * 128];      // [c][h*32+d]
    __shared__ float s_wh[25 * 128];      // [v][hd]
    __shared__ float s_att[4 * 25 * 25 + 64];
    __shared__ float s_e1[100], s_e2[100];
    __shared__ float s_adj[625];

    int n = blockIdx.x;
    int b = n >> 8, t = n & 255;
    int tid = threadIdx.x;

    for (int o = tid; o < 64 * 25; o += 256) {
        int c = o / 25, v = o - c * 25;
        s_x[v * 64 + c] = x[((b * 64 + c) * 256 + t) * 25 + v];
    }
    for (int o = tid; o < 8192; o += 256) {
        int h = o >> 11, rem = o & 2047, c = rem >> 5, d = rem & 31;
        s_wg[c * 128 + h * 32 + d] = wg[o];
    }
    for (int o = tid; o < 625; o += 256) s_adj[o] = adj[o];
    __syncthreads();

    int hd = tid & 127, vh = tid >> 7;
    int v0 = vh * 13, nv = vh ? 12 : 13;

    // Wh[v][hd] = sum_c s_x[v][c] * s_wg[c][hd]
    {
        float acc[13];
#pragma unroll
        for (int i = 0; i < 13; i++) acc[i] = 0.f;
        for (int c = 0; c < 64; c++) {
            float wv = s_wg[c * 128 + hd];
#pragma unroll
            for (int i = 0; i < 13; i++) acc[i] += s_x[(v0 + i) * 64 + c] * wv;
        }
        for (int i = 0; i < nv; i++) s_wh[(v0 + i) * 128 + hd] = acc[i];
    }
    __syncthreads();

    // e1, e2
    if (tid < 200) {
        int which = tid / 100;
        int r = tid - which * 100;
        int h = r / 25, i = r - h * 25;
        const float* a = ag + h * 64 + which * 32;
        float s = 0.f;
#pragma unroll
        for (int d = 0; d < 32; d++) s += s_wh[i * 128 + h * 32 + d] * a[d];
        if (which) s_e2[r] = s; else s_e1[r] = s;
    }
    __syncthreads();

    // masked softmax rows
    if (tid < 100) {
        int h = tid / 25, i = tid - h * 25;
        float ei = s_e1[h * 25 + i];
        float ev[25];
        float mx = -3.4e38f;
#pragma unroll
        for (int j = 0; j < 25; j++) {
            float e = ei + s_e2[h * 25 + j];
            e = e > 0.f ? e : 0.2f * e;
            e = (s_adj[i * 25 + j] > 0.f) ? e : -9.0e15f;
            ev[j] = e;
            mx = fmaxf(mx, e);
        }
        float sum = 0.f;
#pragma unroll
        for (int j = 0; j < 25; j++) { float p = __expf(ev[j] - mx); ev[j] = p; sum += p; }
        float inv = 1.f / sum;
#pragma unroll
        for (int j = 0; j < 25; j++) s_att[(h * 25 + i) * 25 + j] = ev[j] * inv;
    }
    __syncthreads();

    // hp[i][hd] = elu(sum_j att[h][i][j] * Wh[j][hd]); write to xg[b, hd, t, i]
    {
        int h = hd >> 5;
        float acc[13];
#pragma unroll
        for (int i = 0; i < 13; i++) acc[i] = 0.f;
        for (int j = 0; j < 25; j++) {
            float wv = s_wh[j * 128 + hd];
#pragma unroll
            for (int i = 0; i < 13; i++) acc[i] += s_att[(h * 25 + v0 + i) * 25 + j] * wv;
        }
        for (int i = 0; i < nv; i++) {
            float val = acc[i];
            val = val > 0.f ? val : expm1f(val);
            xg[((b * 128 + hd) * 256 + t) * 25 + (v0 + i)] = val;
        }
    }
}

// ---------------- group stats ----------------
// One block per (b*8+g). Group data contiguous: 16 channels * 6400 = 102400 floats.
template <bool RELU>
__global__ __launch_bounds__(256) void stats_kernel(const float* __restrict__ src, float* __restrict__ stats) {
    __shared__ double s_s[256], s_q[256];
    int grp = blockIdx.x;
    const float* p = src + (long long)grp * 102400;
    int tid = threadIdx.x;
    double s = 0.0, q = 0.0;
    for (int o = tid * 4; o < 102400; o += 1024) {
        float4 v = *reinterpret_cast<const float4*>(p + o);
        float a0 = RELU ? fmaxf(v.x, 0.f) : v.x;
        float a1 = RELU ? fmaxf(v.y, 0.f) : v.y;
        float a2 = RELU ? fmaxf(v.z, 0.f) : v.z;
        float a3 = RELU ? fmaxf(v.w, 0.f) : v.w;
        s += (double)a0 + (double)a1 + (double)a2 + (double)a3;
        q += (double)a0 * a0 + (double)a1 * a1 + (double)a2 * a2 + (double)a3 * a3;
    }
    s_s[tid] = s; s_q[tid] = q;
    __syncthreads();
    for (int off = 128; off > 0; off >>= 1) {
        if (tid < off) { s_s[tid] += s_s[tid + off]; s_q[tid] += s_q[tid + off]; }
        __syncthreads();
    }
    if (tid == 0) {
        double m = s_s[0] / 102400.0;
        double var = s_q[0] / 102400.0 - m * m;
        stats[grp] = (float)m;
        stats[256 + grp] = (float)(1.0 / sqrt(var + 1e-5));
    }
}

// ---------------- conv (fused gn1+relu on input) ----------------
template <int K>
__global__ __launch_bounds__(256) void conv_gn_kernel(const float* __restrict__ xg,
                                                      const float* __restrict__ w_rep,
                                                      const float* __restrict__ bb,
                                                      const float* __restrict__ g1,
                                                      const float* __restrict__ b1,
                                                      const float* __restrict__ stats1,
                                                      float* __restrict__ y) {
    __shared__ float s_in[128 * K * 25 + 32];
    __shared__ float s_sc[128], s_bc[128];
    int blk = blockIdx.x;
    int b = blk >> 8, t = blk & 255;
    int tid = threadIdx.x;
    if (tid < 128) {
        int g = tid >> 4;
        float mu = stats1[b * 8 + g], rs = stats1[256 + b * 8 + g];
        float s = rs * g1[tid];
        s_sc[tid] = s;
        s_bc[tid] = b1[tid] - mu * s;
    }
    __syncthreads();
    constexpr int PAD = (K - 1) / 2;
    for (int o = tid; o < 128 * K * 25; o += 256) {
        int ci = o / (K * 25);
        int rem = o - ci * (K * 25);
        int dt = rem / 25;
        int v = rem - dt * 25;
        int tt = t + dt - PAD;
        float val = 0.f;
        if ((unsigned)tt < 256u) {
            float xv = xg[((b * 128 + ci) * 256 + tt) * 25 + v];
            val = fmaxf(0.f, xv * s_sc[ci] + s_bc[ci]);
        }
        s_in[o] = val;
    }
    __syncthreads();
    int co = tid & 127, vh = tid >> 7;
    int v0 = vh * 13, nv = vh ? 12 : 13;
    float bias = bb[co];
    float acc[13];
#pragma unroll
    for (int i = 0; i < 13; i++) acc[i] = bias;
    for (int ci = 0; ci < 128; ++ci) {
#pragma unroll
        for (int dt = 0; dt < K; ++dt) {
            float wv = w_rep[(ci * K + dt) * 128 + co];
            const float* sp = &s_in[(ci * K + dt) * 25 + v0];
#pragma unroll
            for (int i = 0; i < 13; i++) acc[i] += wv * sp[i];
        }
    }
    float* yp = &y[((b * 128 + co) * 256 + t) * 25 + v0];
    for (int i = 0; i < nv; i++) yp[i] = acc[i];
}

// ---------------- res(x) + res_b + fus_b init ----------------
__global__ __launch_bounds__(256) void res_init_kernel(const float* __restrict__ x,
                                                       const float* __restrict__ res_rep,
                                                       const float* __restrict__ res_b,
                                                       const float* __restrict__ fus_b,
                                                       float* __restrict__ acc_out) {
    __shared__ float s_in[64 * 25 + 32];
    int blk = blockIdx.x;
    int b = blk >> 8, t = blk & 255;
    int tid = threadIdx.x;
    for (int o = tid; o < 64 * 25; o += 256) {
        int c = o / 25, v = o - c * 25;
        s_in[o] = x[((b * 64 + c) * 256 + t) * 25 + v];
    }
    __syncthreads();
    int co = tid & 127, vh = tid >> 7;
    int v0 = vh * 13, nv = vh ? 12 : 13;
    float base = res_b[co] + fus_b[co];
    float acc[13];
#pragma unroll
    for (int i = 0; i < 13; i++) acc[i] = base;
    for (int c = 0; c < 64; c++) {
        float wv = res_rep[c * 128 + co];
        const float* sp = &s_in[c * 25 + v0];
#pragma unroll
        for (int i = 0; i < 13; i++) acc[i] += wv * sp[i];
    }
    float* op = &acc_out[((b * 128 + co) * 256 + t) * 25 + v0];
    for (int i = 0; i < nv; i++) op[i] = acc[i];
}

// ---------------- fuse: acc += fus_w_k * gn2(y) ----------------
__global__ __launch_bounds__(256) void fuse_kernel(const float* __restrict__ y,
                                                   const float* __restrict__ fus_rep_k,
                                                   const float* __restrict__ g2,
                                                   const float* __restrict__ b2,
                                                   const float* __restrict__ stats2,
                                                   float* __restrict__ acc_out) {
    __shared__ float s_in[128 * 25 + 32];
    __shared__ float s_sc[128], s_bc[128];
    int blk = blockIdx.x;
    int b = blk >> 8, t = blk & 255;
    int tid = threadIdx.x;
    if (tid < 128) {
        int g = tid >> 4;
        float mu = stats2[b * 8 + g], rs = stats2[256 + b * 8 + g];
        float s = rs * g2[tid];
        s_sc[tid] = s;
        s_bc[tid] = b2[tid] - mu * s;
    }
    __syncthreads();
    for (int o = tid; o < 128 * 25; o += 256) {
        int c = o / 25, v = o - c * 25;
        s_in[o] = y[((b * 128 + c) * 256 + t) * 25 + v] * s_sc[c] + s_bc[c];
    }
    __syncthreads();
    int co = tid & 127, vh = tid >> 7;
    int v0 = vh * 13, nv = vh ? 12 : 13;
    float acc[13];
#pragma unroll
    for (int i = 0; i < 13; i++) acc[i] = 0.f;
    for (int c = 0; c < 128; c++) {
        float wv = fus_rep_k[c * 128 + co];
        const float* sp = &s_in[c * 25 + v0];
#pragma unroll
        for (int i = 0; i < 13; i++) acc[i] += wv * sp[i];
    }
    float* op = &acc_out[((b * 128 + co) * 256 + t) * 25 + v0];
    for (int i = 0; i < nv; i++) op[i] += acc[i];
}

// ---------------- final groupnorm(relu(acc)) ----------------
__global__ __launch_bounds__(256) void final_kernel(const float* __restrict__ acc_in,
                                                    const float* __restrict__ stats3,
                                                    const float* __restrict__ ng,
                                                    const float* __restrict__ nb,
                                                    float* __restrict__ out) {
    long long i4 = (long long)blockIdx.x * 256 + threadIdx.x;
    long long base = i4 * 4;
    if (base >= TENSOR) return;
    int bc = (int)(base / 6400);
    int c = bc & 127;
    int b = bc >> 7;
    int g = c >> 4;
    float mu = stats3[b * 8 + g], rs = stats3[256 + b * 8 + g];
    float s = rs * ng[c];
    float tb = nb[c] - mu * s;
    float4 v = *reinterpret_cast<const float4*>(acc_in + base);
    float4 o;
    o.x = fmaxf(v.x, 0.f) * s + tb;
    o.y = fmaxf(v.y, 0.f) * s + tb;
    o.z = fmaxf(v.z, 0.f) * s + tb;
    o.w = fmaxf(v.w, 0.f) * s + tb;
    *reinterpret_cast<float4*>(out + base) = o;
}

extern "C" void kernel_launch(void* const* d_in, const int* in_sizes, int n_in,
                              void* d_out, int out_size, void* d_ws, size_t ws_size,
                              hipStream_t stream) {
    const float* x      = (const float*)d_in[0];
    const float* adj    = (const float*)d_in[1];
    const float* w_gat  = (const float*)d_in[2];
    const float* a_gat  = (const float*)d_in[3];
    const float* fus_w  = (const float*)d_in[4];
    const float* fus_b  = (const float*)d_in[5];
    const float* res_w  = (const float*)d_in[6];
    const float* res_b  = (const float*)d_in[7];
    const float* norm_g = (const float*)d_in[8];
    const float* norm_b = (const float*)d_in[9];
    // per-branch params at 10 + 6*idx
    const float* tg1[3], *tb1[3], *tw[3], *tbb[3], *tg2[3], *tb2[3];
    for (int i = 0; i < 3; i++) {
        tg1[i] = (const float*)d_in[10 + 6 * i + 0];
        tb1[i] = (const float*)d_in[10 + 6 * i + 1];
        tw[i]  = (const float*)d_in[10 + 6 * i + 2];
        tbb[i] = (const float*)d_in[10 + 6 * i + 3];
        tg2[i] = (const float*)d_in[10 + 6 * i + 4];
        tb2[i] = (const float*)d_in[10 + 6 * i + 5];
    }

    float* ws = (float*)d_ws;
    float* xg      = ws + XG_OFF;
    float* ybuf    = ws + Y_OFF;
    float* acc     = ws + ACC_OFF;
    float* wr[3]   = { ws + WR3_OFF, ws + WR5_OFF, ws + WR7_OFF };
    float* fus_rep = ws + FUSR_OFF;
    float* res_rep = ws + RESR_OFF;
    float* stats1  = ws + STAT1_OFF;
    float* stats2  = ws + STAT2_OFF;
    float* stats3  = ws + STAT3_OFF;

    const int Ks[3] = { 3, 5, 7 };

    // repacks
    for (int i = 0; i < 3; i++) {
        int tot = 128 * 128 * Ks[i];
        repack_conv_kernel<<<(tot + 255) / 256, 256, 0, stream>>>(tw[i], wr[i], Ks[i]);
    }
    repack_mat_kernel<<<(128 * 384 + 255) / 256, 256, 0, stream>>>(fus_w, fus_rep, 128, 384);
    repack_mat_kernel<<<(128 * 64 + 255) / 256, 256, 0, stream>>>(res_w, res_rep, 128, 64);

    // GAT -> xg
    gat_kernel<<<B_ * T_, 256, 0, stream>>>(x, adj, w_gat, a_gat, xg);

    // gn1 stats (shared by all branches)
    stats_kernel<false><<<256, 256, 0, stream>>>(xg, stats1);

    // out_acc = res(x) + res_b + fus_b
    res_init_kernel<<<B_ * T_, 256, 0, stream>>>(x, res_rep, res_b, fus_b, acc);

    // branches
    for (int i = 0; i < 3; i++) {
        if (Ks[i] == 3)
            conv_gn_kernel<3><<<B_ * T_, 256, 0, stream>>>(xg, wr[i], tbb[i], tg1[i], tb1[i], stats1, ybuf);
        else if (Ks[i] == 5)
            conv_gn_kernel<5><<<B_ * T_, 256, 0, stream>>>(xg, wr[i], tbb[i], tg1[i], tb1[i], stats1, ybuf);
        else
            conv_gn_kernel<7><<<B_ * T_, 256, 0, stream>>>(xg, wr[i], tbb[i], tg1[i], tb1[i], stats1, ybuf);
        stats_kernel<false><<<256, 256, 0, stream>>>(ybuf, stats2);
        fuse_kernel<<<B_ * T_, 256, 0, stream>>>(ybuf, fus_rep + (long long)i * 128 * 128,
                                                 tg2[i], tb2[i], stats2, acc);
    }

    // final groupnorm(relu(acc))
    stats_kernel<true><<<256, 256, 0, stream>>>(acc, stats3);
    final_kernel<<<(int)(TENSOR / 4 / 256), 256, 0, stream>>>(acc, stats3, norm_g, norm_b, (float*)d_out);
}

// Round 2
// 1853.529 us; speedup vs baseline: 3.7705x; 3.7705x over previous
//
#include <hip/hip_runtime.h>
#include <math.h>

typedef __bf16 bf16;
typedef __bf16 bf16x8 __attribute__((ext_vector_type(8)));
typedef float  f32x4  __attribute__((ext_vector_type(4)));

// Problem constants
constexpr int B_    = 32;
constexpr int T_    = 256;
constexpr int V_    = 25;
constexpr int NTV   = T_ * V_;                 // 6400
constexpr long long TENSOR = (long long)B_ * 128 * NTV; // 26,214,400 elems

// hbuf padded rows per batch: 76 front pad + 6400 + 76 back pad = 6552
constexpr int HPAD  = 76;
constexpr int HROWS = 6552;

// ws layout (units: float slots)
constexpr long long XG_OFF   = 0;                                   // bf16 [b][c][n]
constexpr long long Y_OFF    = XG_OFF + TENSOR / 2;                 // bf16 [b][co][n]
constexpr long long ACC_OFF  = Y_OFF + TENSOR / 2;                  // fp32 [b][co][n]
constexpr long long HBUF_OFF = ACC_OFF + TENSOR;                    // bf16 [(32*6552+8)][128] swizzled
constexpr long long HBUF_ELEMS = ((long long)B_ * HROWS + 8) * 128;
constexpr long long WB3_OFF  = HBUF_OFF + (HBUF_ELEMS + 1) / 2;
constexpr long long WB5_OFF  = WB3_OFF + 128 * 128 * 3 / 2;
constexpr long long WB7_OFF  = WB5_OFF + 128 * 128 * 5 / 2;
constexpr long long FUSR_OFF = WB7_OFF + 128 * 128 * 7 / 2;
constexpr long long RESR_OFF = FUSR_OFF + 384 * 128;
constexpr long long STAT1_OFF = RESR_OFF + 64 * 128;
constexpr long long STAT2_OFF = STAT1_OFF + 512;
constexpr long long STAT3_OFF = STAT2_OFF + 512;

__device__ __forceinline__ float bfu2f(unsigned short u) {
    return __builtin_bit_cast(float, ((unsigned)u) << 16);
}

// ---------------- repack kernels ----------------
// conv weight (co, ci, k) fp32 -> wr[co][dt][ci] bf16
__global__ void repack_wbf16_kernel(const float* __restrict__ w, bf16* __restrict__ wr, int K) {
    int idx = blockIdx.x * 256 + threadIdx.x;
    int tot = 128 * 128 * K;
    if (idx >= tot) return;
    int co  = idx / (128 * K);
    int rem = idx - co * 128 * K;
    int ci  = rem / K;
    int dt  = rem - ci * K;
    wr[(co * K + dt) * 128 + ci] = (bf16)w[idx];
}

// w[rows][cols] fp32 -> wr[cols][rows] fp32
__global__ void repack_mat_kernel(const float* __restrict__ w, float* __restrict__ wr, int rows, int cols) {
    int idx = blockIdx.x * 256 + threadIdx.x;
    if (idx >= rows * cols) return;
    int r = idx / cols, c = idx - r * cols;
    wr[c * rows + r] = w[idx];
}

// zero the pad rows of hbuf (76 front + 76 back per batch, + 8 slack rows)
__global__ void padzero_kernel(bf16* __restrict__ hbuf) {
    int id = blockIdx.x * 256 + threadIdx.x;
    const int perb = 152 * 16;
    const int tot = 32 * perb + 8 * 16;
    if (id >= tot) return;
    long long row; int chunk;
    if (id < 32 * perb) {
        int b = id / perb, rem = id - b * perb;
        int rr = rem >> 4; chunk = rem & 15;
        int r = rr < HPAD ? rr : (HROWS - HPAD) + (rr - HPAD);
        row = (long long)b * HROWS + r;
    } else {
        int rem = id - 32 * perb;
        row = (long long)32 * HROWS + (rem >> 4); chunk = rem & 15;
    }
    uint4 z = {0u, 0u, 0u, 0u};
    *(uint4*)(hbuf + row * 128 + chunk * 8) = z;
}

// ---------------- GAT kernel (writes bf16 xg) ----------------
__global__ __launch_bounds__(256) void gat_kernel(const float* __restrict__ x,
                                                  const float* __restrict__ adj,
                                                  const float* __restrict__ wg,
                                                  const float* __restrict__ ag,
                                                  bf16* __restrict__ xg) {
    __shared__ float s_x[26 * 64];
    __shared__ float s_wg[64 * 128];
    __shared__ float s_wh[25 * 128];
    __shared__ float s_att[4 * 25 * 25 + 64];
    __shared__ float s_e1[100], s_e2[100];
    __shared__ float s_adj[625];

    int n = blockIdx.x;
    int b = n >> 8, t = n & 255;
    int tid = threadIdx.x;

    for (int o = tid; o < 64 * 25; o += 256) {
        int c = o / 25, v = o - c * 25;
        s_x[v * 64 + c] = x[((b * 64 + c) * 256 + t) * 25 + v];
    }
    for (int o = tid; o < 8192; o += 256) {
        int h = o >> 11, rem = o & 2047, c = rem >> 5, d = rem & 31;
        s_wg[c * 128 + h * 32 + d] = wg[o];
    }
    for (int o = tid; o < 625; o += 256) s_adj[o] = adj[o];
    __syncthreads();

    int hd = tid & 127, vh = tid >> 7;
    int v0 = vh * 13, nv = vh ? 12 : 13;

    {
        float acc[13];
#pragma unroll
        for (int i = 0; i < 13; i++) acc[i] = 0.f;
        for (int c = 0; c < 64; c++) {
            float wv = s_wg[c * 128 + hd];
#pragma unroll
            for (int i = 0; i < 13; i++) acc[i] += s_x[(v0 + i) * 64 + c] * wv;
        }
        for (int i = 0; i < nv; i++) s_wh[(v0 + i) * 128 + hd] = acc[i];
    }
    __syncthreads();

    if (tid < 200) {
        int which = tid / 100;
        int r = tid - which * 100;
        int h = r / 25, i = r - h * 25;
        const float* a = ag + h * 64 + which * 32;
        float s = 0.f;
#pragma unroll
        for (int d = 0; d < 32; d++) s += s_wh[i * 128 + h * 32 + d] * a[d];
        if (which) s_e2[r] = s; else s_e1[r] = s;
    }
    __syncthreads();

    if (tid < 100) {
        int h = tid / 25, i = tid - h * 25;
        float ei = s_e1[h * 25 + i];
        float ev[25];
        float mx = -3.4e38f;
#pragma unroll
        for (int j = 0; j < 25; j++) {
            float e = ei + s_e2[h * 25 + j];
            e = e > 0.f ? e : 0.2f * e;
            e = (s_adj[i * 25 + j] > 0.f) ? e : -9.0e15f;
            ev[j] = e;
            mx = fmaxf(mx, e);
        }
        float sum = 0.f;
#pragma unroll
        for (int j = 0; j < 25; j++) { float p = __expf(ev[j] - mx); ev[j] = p; sum += p; }
        float inv = 1.f / sum;
#pragma unroll
        for (int j = 0; j < 25; j++) s_att[(h * 25 + i) * 25 + j] = ev[j] * inv;
    }
    __syncthreads();

    {
        int h = hd >> 5;
        float acc[13];
#pragma unroll
        for (int i = 0; i < 13; i++) acc[i] = 0.f;
        for (int j = 0; j < 25; j++) {
            float wv = s_wh[j * 128 + hd];
#pragma unroll
            for (int i = 0; i < 13; i++) acc[i] += s_att[(h * 25 + v0 + i) * 25 + j] * wv;
        }
        for (int i = 0; i < nv; i++) {
            float val = acc[i];
            val = val > 0.f ? val : expm1f(val);
            xg[((b * 128 + hd) * 256 + t) * 25 + (v0 + i)] = (bf16)val;
        }
    }
}

// ---------------- group stats ----------------
// fp32 variant (for acc, with relu)
template <bool RELU>
__global__ __launch_bounds__(256) void stats_kernel(const float* __restrict__ src, float* __restrict__ stats) {
    __shared__ double s_s[256], s_q[256];
    int grp = blockIdx.x;
    const float* p = src + (long long)grp * 102400;
    int tid = threadIdx.x;
    double s = 0.0, q = 0.0;
    for (int o = tid * 4; o < 102400; o += 1024) {
        float4 v = *reinterpret_cast<const float4*>(p + o);
        float a0 = RELU ? fmaxf(v.x, 0.f) : v.x;
        float a1 = RELU ? fmaxf(v.y, 0.f) : v.y;
        float a2 = RELU ? fmaxf(v.z, 0.f) : v.z;
        float a3 = RELU ? fmaxf(v.w, 0.f) : v.w;
        s += (double)a0 + (double)a1 + (double)a2 + (double)a3;
        q += (double)a0 * a0 + (double)a1 * a1 + (double)a2 * a2 + (double)a3 * a3;
    }
    s_s[tid] = s; s_q[tid] = q;
    __syncthreads();
    for (int off = 128; off > 0; off >>= 1) {
        if (tid < off) { s_s[tid] += s_s[tid + off]; s_q[tid] += s_q[tid + off]; }
        __syncthreads();
    }
    if (tid == 0) {
        double m = s_s[0] / 102400.0;
        double var = s_q[0] / 102400.0 - m * m;
        stats[grp] = (float)m;
        stats[256 + grp] = (float)(1.0 / sqrt(var + 1e-5));
    }
}

// bf16 variant (xg, y) — group-contiguous layout [b][c][n]
__global__ __launch_bounds__(256) void stats_bf16_kernel(const bf16* __restrict__ src, float* __restrict__ stats) {
    __shared__ double s_s[256], s_q[256];
    int grp = blockIdx.x, tid = threadIdx.x;
    const unsigned short* p = (const unsigned short*)src + (long long)grp * 102400;
    double s = 0.0, q = 0.0;
    for (int o = tid * 8; o < 102400; o += 2048) {
        uint4 u = *reinterpret_cast<const uint4*>(p + o);
        unsigned w[4] = {u.x, u.y, u.z, u.w};
#pragma unroll
        for (int j = 0; j < 4; ++j) {
            float f0 = __builtin_bit_cast(float, (w[j] & 0xffffu) << 16);
            float f1 = __builtin_bit_cast(float, w[j] & 0xffff0000u);
            s += (double)f0 + (double)f1;
            q += (double)f0 * f0 + (double)f1 * f1;
        }
    }
    s_s[tid] = s; s_q[tid] = q;
    __syncthreads();
    for (int off = 128; off > 0; off >>= 1) {
        if (tid < off) { s_s[tid] += s_s[tid + off]; s_q[tid] += s_q[tid + off]; }
        __syncthreads();
    }
    if (tid == 0) {
        double m = s_s[0] / 102400.0;
        double var = s_q[0] / 102400.0 - m * m;
        stats[grp] = (float)m;
        stats[256 + grp] = (float)(1.0 / sqrt(var + 1e-5));
    }
}

// ---------------- h = relu(gn1(xg)) -> hbuf bf16 [b][row][ci] (chunk-swizzled) ----------------
__global__ __launch_bounds__(256) void hgen_kernel(const bf16* __restrict__ xg,
                                                   const float* __restrict__ g1,
                                                   const float* __restrict__ b1,
                                                   const float* __restrict__ stats1,
                                                   bf16* __restrict__ hbuf) {
    __shared__ bf16 s_t[64 * 128];   // [n_local][ci]
    int tile = blockIdx.x, b = blockIdx.y, tid = threadIdx.x;
    int n0 = tile * 64;
    // phase 1: read xg[b][ci][n0..n0+63], apply gn1+relu, transpose into LDS
    for (int it = 0; it < 4; ++it) {
        int ci = it * 32 + (tid >> 3);
        int c8 = tid & 7;
        int g = ci >> 4;
        float mu = stats1[b * 8 + g], rs = stats1[256 + b * 8 + g];
        float sc = rs * g1[ci], bc = b1[ci] - mu * sc;
        const unsigned short* src = (const unsigned short*)xg + ((long long)(b * 128 + ci)) * 6400 + n0 + c8 * 8;
        uint4 u = *(const uint4*)src;
        unsigned w[4] = {u.x, u.y, u.z, u.w};
#pragma unroll
        for (int p = 0; p < 4; ++p) {
            float f0 = __builtin_bit_cast(float, (w[p] & 0xffffu) << 16);
            float f1 = __builtin_bit_cast(float, w[p] & 0xffff0000u);
            f0 = fmaxf(0.f, f0 * sc + bc);
            f1 = fmaxf(0.f, f1 * sc + bc);
            int nl = c8 * 8 + p * 2;
            s_t[nl * 128 + ci] = (bf16)f0;
            s_t[(nl + 1) * 128 + ci] = (bf16)f1;
        }
    }
    __syncthreads();
    // phase 2: write rows to global with 16B-chunk XOR swizzle (pos = q ^ (r&15))
    long long rowbase = (long long)b * HROWS;
    for (int w = tid; w < 1024; w += 256) {
        int rl = w >> 4, cpos = w & 15;
        int r = n0 + rl + HPAD;
        int q = cpos ^ (r & 15);
        uint4 d = *(const uint4*)(s_t + rl * 128 + q * 8);
        *(uint4*)(hbuf + (rowbase + r) * 128 + cpos * 8) = d;
    }
}

// ---------------- conv as MFMA GEMM ----------------
// y[b][co][n] bf16 = bias[co] + sum_{ci,dt} w[co][ci][dt] * h[b][n + (dt-P)*25][ci]
template <int K>
__global__ __launch_bounds__(256, 2) void conv_mfma_kernel(const bf16* __restrict__ hbuf,
                                                           const bf16* __restrict__ wr,
                                                           const float* __restrict__ bb,
                                                           bf16* __restrict__ y) {
    constexpr int P = (K - 1) / 2;
    constexpr int RAW = 64 + (K - 1) * 25;
    constexpr int ROWS = (RAW + 3) & ~3;
    constexpr int ISSUES = ROWS / 4;          // each issue: 64 lanes x 16B = 4 rows
    __shared__ bf16 s_h[ROWS * 128];
    int tile = blockIdx.x, b = blockIdx.y, tid = threadIdx.x;
    int wid = tid >> 6, lane = tid & 63;
    int r0 = tile * 64 + HPAD - P * 25;
    const bf16* gsrc = hbuf + ((long long)b * HROWS + r0) * 128;
    for (int i = wid; i < ISSUES; i += 4) {
        __builtin_amdgcn_global_load_lds(
            (const __attribute__((address_space(1))) unsigned int*)(gsrc + i * 512 + lane * 8),
            (__attribute__((address_space(3))) unsigned int*)(s_h + i * 512),
            16, 0, 0);
    }
    __syncthreads();

    int l15 = lane & 15, l4 = lane >> 4;
    int co0 = wid * 32;
    f32x4 acc[2][4];
#pragma unroll
    for (int m = 0; m < 2; ++m)
#pragma unroll
        for (int ns = 0; ns < 4; ++ns) acc[m][ns] = f32x4{0.f, 0.f, 0.f, 0.f};

    for (int dt = 0; dt < K; ++dt) {
#pragma unroll
        for (int cb = 0; cb < 4; ++cb) {
            const bf16* ap = wr + ((co0 + l15) * K + dt) * 128 + cb * 32 + l4 * 8;
            bf16x8 a0 = *(const bf16x8*)ap;
            bf16x8 a1 = *(const bf16x8*)(ap + 16 * K * 128);
#pragma unroll
            for (int ns = 0; ns < 4; ++ns) {
                int row = ns * 16 + l15 + dt * 25;
                int chunk = (cb * 4 + l4) ^ ((r0 + row) & 15);
                bf16x8 bv = *(const bf16x8*)(s_h + row * 128 + chunk * 8);
                acc[0][ns] = __builtin_amdgcn_mfma_f32_16x16x32_bf16(a0, bv, acc[0][ns], 0, 0, 0);
                acc[1][ns] = __builtin_amdgcn_mfma_f32_16x16x32_bf16(a1, bv, acc[1][ns], 0, 0, 0);
            }
        }
    }

    float bias[2][4];
#pragma unroll
    for (int m = 0; m < 2; ++m)
#pragma unroll
        for (int r = 0; r < 4; ++r) bias[m][r] = bb[co0 + m * 16 + l4 * 4 + r];
#pragma unroll
    for (int m = 0; m < 2; ++m)
#pragma unroll
        for (int ns = 0; ns < 4; ++ns) {
            int n = tile * 64 + ns * 16 + l15;
#pragma unroll
            for (int r = 0; r < 4; ++r) {
                int co = co0 + m * 16 + l4 * 4 + r;
                y[(b * 128 + co) * 6400 + n] = (bf16)(acc[m][ns][r] + bias[m][r]);
            }
        }
}

// ---------------- res(x) + res_b + fus_b init (fp32) ----------------
__global__ __launch_bounds__(256) void res_init_kernel(const float* __restrict__ x,
                                                       const float* __restrict__ res_rep,
                                                       const float* __restrict__ res_b,
                                                       const float* __restrict__ fus_b,
                                                       float* __restrict__ acc_out) {
    __shared__ float s_in[64 * 25 + 32];
    int blk = blockIdx.x;
    int b = blk >> 8, t = blk & 255;
    int tid = threadIdx.x;
    for (int o = tid; o < 64 * 25; o += 256) {
        int c = o / 25, v = o - c * 25;
        s_in[o] = x[((b * 64 + c) * 256 + t) * 25 + v];
    }
    __syncthreads();
    int co = tid & 127, vh = tid >> 7;
    int v0 = vh * 13, nv = vh ? 12 : 13;
    float base = res_b[co] + fus_b[co];
    float acc[13];
#pragma unroll
    for (int i = 0; i < 13; i++) acc[i] = base;
    for (int c = 0; c < 64; c++) {
        float wv = res_rep[c * 128 + co];
        const float* sp = &s_in[c * 25 + v0];
#pragma unroll
        for (int i = 0; i < 13; i++) acc[i] += wv * sp[i];
    }
    float* op = &acc_out[((b * 128 + co) * 256 + t) * 25 + v0];
    for (int i = 0; i < nv; i++) op[i] = acc[i];
}

// ---------------- fuse: acc += fus_w_k * gn2(y)  (y is bf16) ----------------
__global__ __launch_bounds__(256) void fuse_kernel(const bf16* __restrict__ y,
                                                   const float* __restrict__ fus_rep_k,
                                                   const float* __restrict__ g2,
                                                   const float* __restrict__ b2,
                                                   const float* __restrict__ stats2,
                                                   float* __restrict__ acc_out) {
    __shared__ float s_in[128 * 25 + 32];
    __shared__ float s_sc[128], s_bc[128];
    int blk = blockIdx.x;
    int b = blk >> 8, t = blk & 255;
    int tid = threadIdx.x;
    if (tid < 128) {
        int g = tid >> 4;
        float mu = stats2[b * 8 + g], rs = stats2[256 + b * 8 + g];
        float s = rs * g2[tid];
        s_sc[tid] = s;
        s_bc[tid] = b2[tid] - mu * s;
    }
    __syncthreads();
    for (int o = tid; o < 128 * 25; o += 256) {
        int c = o / 25, v = o - c * 25;
        float yv = (float)y[((b * 128 + c) * 256 + t) * 25 + v];
        s_in[o] = yv * s_sc[c] + s_bc[c];
    }
    __syncthreads();
    int co = tid & 127, vh = tid >> 7;
    int v0 = vh * 13, nv = vh ? 12 : 13;
    float acc[13];
#pragma unroll
    for (int i = 0; i < 13; i++) acc[i] = 0.f;
    for (int c = 0; c < 128; c++) {
        float wv = fus_rep_k[c * 128 + co];
        const float* sp = &s_in[c * 25 + v0];
#pragma unroll
        for (int i = 0; i < 13; i++) acc[i] += wv * sp[i];
    }
    float* op = &acc_out[((b * 128 + co) * 256 + t) * 25 + v0];
    for (int i = 0; i < nv; i++) op[i] += acc[i];
}

// ---------------- final groupnorm(relu(acc)) ----------------
__global__ __launch_bounds__(256) void final_kernel(const float* __restrict__ acc_in,
                                                    const float* __restrict__ stats3,
                                                    const float* __restrict__ ng,
                                                    const float* __restrict__ nb,
                                                    float* __restrict__ out) {
    long long i4 = (long long)blockIdx.x * 256 + threadIdx.x;
    long long base = i4 * 4;
    if (base >= TENSOR) return;
    int bc = (int)(base / 6400);
    int c = bc & 127;
    int b = bc >> 7;
    int g = c >> 4;
    float mu = stats3[b * 8 + g], rs = stats3[256 + b * 8 + g];
    float s = rs * ng[c];
    float tb = nb[c] - mu * s;
    float4 v = *reinterpret_cast<const float4*>(acc_in + base);
    float4 o;
    o.x = fmaxf(v.x, 0.f) * s + tb;
    o.y = fmaxf(v.y, 0.f) * s + tb;
    o.z = fmaxf(v.z, 0.f) * s + tb;
    o.w = fmaxf(v.w, 0.f) * s + tb;
    *reinterpret_cast<float4*>(out + base) = o;
}

extern "C" void kernel_launch(void* const* d_in, const int* in_sizes, int n_in,
                              void* d_out, int out_size, void* d_ws, size_t ws_size,
                              hipStream_t stream) {
    const float* x      = (const float*)d_in[0];
    const float* adj    = (const float*)d_in[1];
    const float* w_gat  = (const float*)d_in[2];
    const float* a_gat  = (const float*)d_in[3];
    const float* fus_w  = (const float*)d_in[4];
    const float* fus_b  = (const float*)d_in[5];
    const float* res_w  = (const float*)d_in[6];
    const float* res_b  = (const float*)d_in[7];
    const float* norm_g = (const float*)d_in[8];
    const float* norm_b = (const float*)d_in[9];
    const float* tg1[3], *tb1[3], *tw[3], *tbb[3], *tg2[3], *tb2[3];
    for (int i = 0; i < 3; i++) {
        tg1[i] = (const float*)d_in[10 + 6 * i + 0];
        tb1[i] = (const float*)d_in[10 + 6 * i + 1];
        tw[i]  = (const float*)d_in[10 + 6 * i + 2];
        tbb[i] = (const float*)d_in[10 + 6 * i + 3];
        tg2[i] = (const float*)d_in[10 + 6 * i + 4];
        tb2[i] = (const float*)d_in[10 + 6 * i + 5];
    }

    float* ws = (float*)d_ws;
    bf16* xg     = (bf16*)(ws + XG_OFF);
    bf16* ybuf   = (bf16*)(ws + Y_OFF);
    float* acc   = ws + ACC_OFF;
    bf16* hbuf   = (bf16*)(ws + HBUF_OFF);
    bf16* wrb[3] = { (bf16*)(ws + WB3_OFF), (bf16*)(ws + WB5_OFF), (bf16*)(ws + WB7_OFF) };
    float* fus_rep = ws + FUSR_OFF;
    float* res_rep = ws + RESR_OFF;
    float* stats1  = ws + STAT1_OFF;
    float* stats2  = ws + STAT2_OFF;
    float* stats3  = ws + STAT3_OFF;

    const int Ks[3] = { 3, 5, 7 };

    // repacks
    for (int i = 0; i < 3; i++) {
        int tot = 128 * 128 * Ks[i];
        repack_wbf16_kernel<<<(tot + 255) / 256, 256, 0, stream>>>(tw[i], wrb[i], Ks[i]);
    }
    repack_mat_kernel<<<(128 * 384 + 255) / 256, 256, 0, stream>>>(fus_w, fus_rep, 128, 384);
    repack_mat_kernel<<<(128 * 64 + 255) / 256, 256, 0, stream>>>(res_w, res_rep, 128, 64);
    padzero_kernel<<<305, 256, 0, stream>>>(hbuf);

    // GAT -> xg (bf16)
    gat_kernel<<<B_ * T_, 256, 0, stream>>>(x, adj, w_gat, a_gat, xg);

    // gn1 stats (branch-independent)
    stats_bf16_kernel<<<256, 256, 0, stream>>>(xg, stats1);

    // out_acc = res(x) + res_b + fus_b
    res_init_kernel<<<B_ * T_, 256, 0, stream>>>(x, res_rep, res_b, fus_b, acc);

    dim3 g2d(100, 32);
    for (int i = 0; i < 3; i++) {
        hgen_kernel<<<g2d, 256, 0, stream>>>(xg, tg1[i], tb1[i], stats1, hbuf);
        if (Ks[i] == 3)
            conv_mfma_kernel<3><<<g2d, 256, 0, stream>>>(hbuf, wrb[i], tbb[i], ybuf);
        else if (Ks[i] == 5)
            conv_mfma_kernel<5><<<g2d, 256, 0, stream>>>(hbuf, wrb[i], tbb[i], ybuf);
        else
            conv_mfma_kernel<7><<<g2d, 256, 0, stream>>>(hbuf, wrb[i], tbb[i], ybuf);
        stats_bf16_kernel<<<256, 256, 0, stream>>>(ybuf, stats2);
        fuse_kernel<<<B_ * T_, 256, 0, stream>>>(ybuf, fus_rep + (long long)i * 128 * 128,
                                                 tg2[i], tb2[i], stats2, acc);
    }

    stats_kernel<true><<<256, 256, 0, stream>>>(acc, stats3);
    final_kernel<<<(int)(TENSOR / 4 / 256), 256, 0, stream>>>(acc, stats3, norm_g, norm_b, (float*)d_out);
}

// Round 4
// 761.742 us; speedup vs baseline: 9.1748x; 2.4333x over previous
//
#include <hip/hip_runtime.h>
#include <math.h>

typedef __bf16 bf16;
typedef __bf16 bf16x8 __attribute__((ext_vector_type(8)));
typedef float  f32x4  __attribute__((ext_vector_type(4)));

// Problem constants
constexpr int B_   = 32;
constexpr int T_   = 256;
constexpr int V_   = 25;
constexpr int NTV  = T_ * V_;                 // 6400
constexpr long long TENSOR = (long long)B_ * 128 * NTV; // 26,214,400 elems

// ws layout (float slots).
// Aliased region [0, TENSOR): holds xgt (bf16) + conv weights + wgr during the
// first phase; fuse_mfma overwrites it with fp32 acc (all prior tenants dead).
constexpr long long ACC_OFF  = 0;                        // fp32 [32][6400][128]
constexpr long long XGT_OFF  = 0;                        // bf16 [32][6400][128] (dead after convs)
constexpr long long WRB3_OFF = XGT_OFF + TENSOR / 2;     // bf16 conv w (dead after convs)
constexpr long long WRB5_OFF = WRB3_OFF + 128 * 128 * 3 / 2;
constexpr long long WRB7_OFF = WRB5_OFF + 128 * 128 * 5 / 2;
constexpr long long WGR_OFF  = WRB7_OFF + 128 * 128 * 7 / 2;  // fp32 8192 (dead after gat)
// Non-aliased tail:
constexpr long long Y0_OFF   = ACC_OFF + TENSOR;         // bf16 x3 [32][6400][128]
constexpr long long Y1_OFF   = Y0_OFF + TENSOR / 2;
constexpr long long Y2_OFF   = Y1_OFF + TENSOR / 2;
constexpr long long XT_OFF   = Y2_OFF + TENSOR / 2;      // bf16 [32][6400][64]
constexpr long long ABIG_OFF = XT_OFF + TENSOR / 4;      // bf16 [32][128][448]
constexpr long long BIAS_OFF = ABIG_OFF + (32LL * 128 * 448) / 2; // f32 [32][128]
constexpr long long STATS_OFF = BIAS_OFF + 4096;         // 5 x 512 floats

__device__ __forceinline__ float bflo(unsigned u) { return __builtin_bit_cast(float, u << 16); }
__device__ __forceinline__ float bfhi(unsigned u) { return __builtin_bit_cast(float, u & 0xffff0000u); }
__device__ __forceinline__ unsigned packbf2(float a, float b) {
    unsigned short ua = __builtin_bit_cast(unsigned short, (bf16)a);
    unsigned short ub = __builtin_bit_cast(unsigned short, (bf16)b);
    return (unsigned)ua | ((unsigned)ub << 16);
}

// ---------------- small prep kernels ----------------
__global__ void zero_stats_kernel(float* __restrict__ st) {
    int t = threadIdx.x;
    for (int o = t; o < 2560; o += 256) st[o] = 0.f;
}

// conv weight (co, ci, k) fp32 -> wr[co][dt][ci] bf16
__global__ void repack_wbf16_kernel(const float* __restrict__ w, bf16* __restrict__ wr, int K) {
    int idx = blockIdx.x * 256 + threadIdx.x;
    int tot = 128 * 128 * K;
    if (idx >= tot) return;
    int co  = idx / (128 * K);
    int rem = idx - co * 128 * K;
    int ci  = rem / K;
    int dt  = rem - ci * K;
    wr[(co * K + dt) * 128 + ci] = (bf16)w[idx];
}

// wg [h][c][d] fp32 -> wgr[c][h*32+d] fp32
__global__ void repack_wg_kernel(const float* __restrict__ wg, float* __restrict__ wgr) {
    int o = blockIdx.x * 256 + threadIdx.x;
    if (o >= 8192) return;
    int h = o >> 11, rem = o & 2047, c = rem >> 5, d = o & 31;
    wgr[c * 128 + h * 32 + d] = wg[o];
}

// x fp32 [b][64][n] -> xt bf16 [b][n][64]
__global__ __launch_bounds__(256) void xt_kernel(const float* __restrict__ x, bf16* __restrict__ xt) {
    __shared__ bf16 s_t[64 * 72];
    int tile = blockIdx.x, b = blockIdx.y, tid = threadIdx.x;
    int n0 = tile * 64;
#pragma unroll
    for (int it = 0; it < 4; ++it) {
        int flat = it * 256 + tid;
        int c = flat >> 4, q = flat & 15;
        float4 v = *reinterpret_cast<const float4*>(x + ((b * 64 + c) * NTV) + n0 + q * 4);
        s_t[(q * 4 + 0) * 72 + c] = (bf16)v.x;
        s_t[(q * 4 + 1) * 72 + c] = (bf16)v.y;
        s_t[(q * 4 + 2) * 72 + c] = (bf16)v.z;
        s_t[(q * 4 + 3) * 72 + c] = (bf16)v.w;
    }
    __syncthreads();
#pragma unroll
    for (int it = 0; it < 2; ++it) {
        int flat = it * 256 + tid;
        int nl = flat >> 3, c8 = flat & 7;
        uint4 v = *reinterpret_cast<const uint4*>(s_t + nl * 72 + c8 * 8);
        *reinterpret_cast<uint4*>(xt + ((long long)(b * NTV + n0 + nl)) * 64 + c8 * 8) = v;
    }
}

// ---------------- GAT kernel -> xgt [b][n][128] ----------------
__global__ __launch_bounds__(256) void gat_kernel(const float* __restrict__ x,
                                                  const float* __restrict__ adj,
                                                  const float* __restrict__ wgr,
                                                  const float* __restrict__ ag,
                                                  bf16* __restrict__ xgt) {
    __shared__ float s_x[64 * 25];      // [c][v]
    __shared__ float s_wh[25 * 129];    // [v][hd], pad 129
    __shared__ float s_att[4 * 25 * 25];
    __shared__ float s_e1[100], s_e2[100];
    __shared__ float s_adj[625];

    int n = blockIdx.x;
    int b = n >> 8, t = n & 255;
    int tid = threadIdx.x;

    for (int o = tid; o < 1600; o += 256) {
        int c = o / 25, v = o - c * 25;
        s_x[o] = x[(b * 64 + c) * NTV + t * 25 + v];
    }
    for (int o = tid; o < 625; o += 256) s_adj[o] = adj[o];
    __syncthreads();

    int hd = tid & 127, vh = tid >> 7;
    int v0 = vh * 13, nv = vh ? 12 : 13;

    // Wh[v][hd]
    {
        float acc[13];
#pragma unroll
        for (int i = 0; i < 13; i++) acc[i] = 0.f;
        for (int c = 0; c < 64; c++) {
            float wv = wgr[c * 128 + hd];
#pragma unroll
            for (int i = 0; i < 13; i++) acc[i] += s_x[c * 25 + v0 + i] * wv;
        }
        for (int i = 0; i < nv; i++) s_wh[(v0 + i) * 129 + hd] = acc[i];
    }
    __syncthreads();

    if (tid < 200) {
        int which = tid / 100;
        int r = tid - which * 100;
        int h = r / 25, i = r - h * 25;
        const float* a = ag + h * 64 + which * 32;
        float s = 0.f;
#pragma unroll
        for (int d = 0; d < 32; d++) s += s_wh[i * 129 + h * 32 + d] * a[d];
        if (which) s_e2[r] = s; else s_e1[r] = s;
    }
    __syncthreads();

    if (tid < 100) {
        int h = tid / 25, i = tid - h * 25;
        float ei = s_e1[h * 25 + i];
        float ev[25];
        float mx = -3.4e38f;
#pragma unroll
        for (int j = 0; j < 25; j++) {
            float e = ei + s_e2[h * 25 + j];
            e = e > 0.f ? e : 0.2f * e;
            e = (s_adj[i * 25 + j] > 0.f) ? e : -9.0e15f;
            ev[j] = e;
            mx = fmaxf(mx, e);
        }
        float sum = 0.f;
#pragma unroll
        for (int j = 0; j < 25; j++) { float p = __expf(ev[j] - mx); ev[j] = p; sum += p; }
        float inv = 1.f / sum;
#pragma unroll
        for (int j = 0; j < 25; j++) s_att[(h * 25 + i) * 25 + j] = ev[j] * inv;
    }
    __syncthreads();

    {
        int h = hd >> 5;
        float acc[13];
#pragma unroll
        for (int i = 0; i < 13; i++) acc[i] = 0.f;
        for (int j = 0; j < 25; j++) {
            float wv = s_wh[j * 129 + hd];
#pragma unroll
            for (int i = 0; i < 13; i++) acc[i] += s_att[(h * 25 + v0 + i) * 25 + j] * wv;
        }
        for (int i = 0; i < nv; i++) {
            float val = acc[i];
            val = val > 0.f ? val : expm1f(val);
            xgt[((long long)(b * NTV + t * 25 + v0 + i)) * 128 + hd] = (bf16)val;
        }
    }
}

// ---------------- group stats on [b][n][128] bf16 ----------------
template <bool RELU>
__global__ __launch_bounds__(256) void stats_c128_kernel(const bf16* __restrict__ src, float* __restrict__ raw) {
    __shared__ float s_s[256], s_q[256];
    int b = blockIdx.x, sl = blockIdx.y, tid = threadIdx.x;
    int ch = tid & 15;
    const bf16* base = src + ((long long)(b * NTV + sl * 400 + (tid >> 4))) * 128 + ch * 8;
    float s = 0.f, q = 0.f;
    for (int it = 0; it < 25; ++it) {
        uint4 v = *reinterpret_cast<const uint4*>(base + (long long)it * 16 * 128);
        unsigned w[4] = {v.x, v.y, v.z, v.w};
#pragma unroll
        for (int p = 0; p < 4; ++p) {
            float f0 = bflo(w[p]), f1 = bfhi(w[p]);
            if (RELU) { f0 = fmaxf(f0, 0.f); f1 = fmaxf(f1, 0.f); }
            s += f0 + f1;
            q += f0 * f0 + f1 * f1;
        }
    }
    s_s[tid] = s; s_q[tid] = q;
    __syncthreads();
    if (tid < 8) {
        float ss = 0.f, qq = 0.f;
        for (int i = 0; i < 16; ++i) {
            int j = i * 16 + tid * 2;
            ss += s_s[j] + s_s[j + 1];
            qq += s_q[j] + s_q[j + 1];
        }
        atomicAdd(&raw[b * 8 + tid], ss);
        atomicAdd(&raw[256 + b * 8 + tid], qq);
    }
}

// group stats on [b][n][128] fp32 (with relu) — for the fused accumulator
__global__ __launch_bounds__(256) void stats_f32_relu_kernel(const float* __restrict__ src, float* __restrict__ raw) {
    __shared__ float s_s[256], s_q[256];
    int b = blockIdx.x, sl = blockIdx.y, tid = threadIdx.x;
    int cq = tid & 31;                   // 32 chunks of 4 channels
    int r0 = sl * 400 + (tid >> 5);      // 8 row-phases
    const float* base = src + ((long long)(b * NTV + r0)) * 128 + cq * 4;
    float s = 0.f, q = 0.f;
    for (int it = 0; it < 50; ++it) {
        float4 v = *reinterpret_cast<const float4*>(base + (long long)it * 8 * 128);
        float f0 = fmaxf(v.x, 0.f), f1 = fmaxf(v.y, 0.f);
        float f2 = fmaxf(v.z, 0.f), f3 = fmaxf(v.w, 0.f);
        s += f0 + f1 + f2 + f3;
        q += f0 * f0 + f1 * f1 + f2 * f2 + f3 * f3;
    }
    s_s[tid] = s; s_q[tid] = q;
    __syncthreads();
    // thread's 4 channels (4*cq..4*cq+3) all belong to group cq>>2
    if (tid < 8) {
        float ss = 0.f, qq = 0.f;
        for (int k = 0; k < 8; ++k)
            for (int j = 0; j < 4; ++j) {
                int t = k * 32 + tid * 4 + j;
                ss += s_s[t]; qq += s_q[t];
            }
        atomicAdd(&raw[b * 8 + tid], ss);
        atomicAdd(&raw[256 + b * 8 + tid], qq);
    }
}

__global__ void finalize_kernel(float* __restrict__ raw) {
    float* p = raw + blockIdx.x * 512;
    int t = threadIdx.x;
    float s = p[t], q = p[256 + t];
    float mu = s * (1.f / 102400.f);
    float var = q * (1.f / 102400.f) - mu * mu;
    p[t] = mu;
    p[256 + t] = rsqrtf(var + 1e-5f);
}

// ---------------- conv as MFMA GEMM (gn1+relu fused at staging) ----------------
template <int K>
__global__ __launch_bounds__(256) void conv_mfma_kernel(const bf16* __restrict__ xgt,
                                                        const bf16* __restrict__ wr,
                                                        const float* __restrict__ bb,
                                                        const float* __restrict__ g1,
                                                        const float* __restrict__ b1,
                                                        const float* __restrict__ stats1,
                                                        bf16* __restrict__ y) {
    constexpr int P = (K - 1) / 2;
    constexpr int ROWS = 128 + (K - 1) * 25;
    constexpr int NCH = ROWS * 16;
    constexpr int ITERS = (NCH + 255) / 256;
    __shared__ bf16 s_h[ROWS * 128];   // reused as s_y (128*136 <= ROWS*128 for K>=3)
    __shared__ float s_sc[128], s_bc[128];

    int tile = blockIdx.x, b = blockIdx.y, tid = threadIdx.x;
    int n0 = tile * 128;
    if (tid < 128) {
        int g = tid >> 4;
        float mu = stats1[b * 8 + g], rs = stats1[256 + b * 8 + g];
        float sc = rs * g1[tid];
        s_sc[tid] = sc;
        s_bc[tid] = b1[tid] - mu * sc;
    }
    __syncthreads();

    int ch = tid & 15;
    float sc8[8], bc8[8];
#pragma unroll
    for (int j = 0; j < 8; ++j) { sc8[j] = s_sc[ch * 8 + j]; bc8[j] = s_bc[ch * 8 + j]; }

    int nb = b * NTV;
    for (int it = 0; it < ITERS; ++it) {
        int flat = it * 256 + tid;
        if (flat < NCH) {
            int r = flat >> 4;
            int n = n0 - P * 25 + r;
            uint4 v = {0u, 0u, 0u, 0u};
            if ((unsigned)n < (unsigned)NTV)
                v = *reinterpret_cast<const uint4*>(xgt + ((long long)(nb + n)) * 128 + ch * 8);
            unsigned w[4] = {v.x, v.y, v.z, v.w};
            uint4 o;
            unsigned* op = &o.x;
#pragma unroll
            for (int p = 0; p < 4; ++p) {
                float f0 = fmaxf(bflo(w[p]) * sc8[2 * p] + bc8[2 * p], 0.f);
                float f1 = fmaxf(bfhi(w[p]) * sc8[2 * p + 1] + bc8[2 * p + 1], 0.f);
                op[p] = packbf2(f0, f1);
            }
            *reinterpret_cast<uint4*>(s_h + r * 128 + (ch ^ (r & 15)) * 8) = o;
        }
    }
    __syncthreads();

    int wid = tid >> 6, lane = tid & 63, l15 = lane & 15, l4 = lane >> 4;
    int co0 = wid * 32;
    f32x4 acc[2][8];
#pragma unroll
    for (int m = 0; m < 2; ++m)
#pragma unroll
        for (int ns = 0; ns < 8; ++ns) acc[m][ns] = f32x4{0.f, 0.f, 0.f, 0.f};

    for (int dt = 0; dt < K; ++dt) {
#pragma unroll
        for (int cb = 0; cb < 4; ++cb) {
            const bf16* ap = wr + ((co0 + l15) * K + dt) * 128 + cb * 32 + l4 * 8;
            bf16x8 a0 = *(const bf16x8*)ap;
            bf16x8 a1 = *(const bf16x8*)(ap + 16 * K * 128);
#pragma unroll
            for (int ns = 0; ns < 8; ++ns) {
                int r = ns * 16 + l15 + dt * 25;
                int chunk = (cb * 4 + l4) ^ (r & 15);
                bf16x8 bv = *(const bf16x8*)(s_h + r * 128 + chunk * 8);
                acc[0][ns] = __builtin_amdgcn_mfma_f32_16x16x32_bf16(a0, bv, acc[0][ns], 0, 0, 0);
                acc[1][ns] = __builtin_amdgcn_mfma_f32_16x16x32_bf16(a1, bv, acc[1][ns], 0, 0, 0);
            }
        }
    }
    __syncthreads();   // s_h -> s_y reuse

    bf16* sy = s_h;
    float bias[2][4];
#pragma unroll
    for (int m = 0; m < 2; ++m)
#pragma unroll
        for (int rr = 0; rr < 4; ++rr) bias[m][rr] = bb[co0 + m * 16 + l4 * 4 + rr];
#pragma unroll
    for (int m = 0; m < 2; ++m)
#pragma unroll
        for (int ns = 0; ns < 8; ++ns) {
            int nl = ns * 16 + l15;
            uint2 pk;
            pk.x = packbf2(acc[m][ns][0] + bias[m][0], acc[m][ns][1] + bias[m][1]);
            pk.y = packbf2(acc[m][ns][2] + bias[m][2], acc[m][ns][3] + bias[m][3]);
            *reinterpret_cast<uint2*>(sy + nl * 136 + co0 + m * 16 + l4 * 4) = pk;
        }
    __syncthreads();
#pragma unroll
    for (int it = 0; it < 8; ++it) {
        int flat = it * 256 + tid;
        int nl = flat >> 4, c2 = flat & 15;
        uint4 v = *reinterpret_cast<const uint4*>(sy + nl * 136 + c2 * 8);
        *reinterpret_cast<uint4*>(y + ((long long)(nb + n0 + nl)) * 128 + c2 * 8) = v;
    }
}

// ---------------- fold gn2 into fusion weights (per batch) ----------------
__global__ __launch_bounds__(256) void fold_kernel(const float* __restrict__ fus_w, const float* __restrict__ fus_b,
                                                   const float* __restrict__ res_w, const float* __restrict__ res_b,
                                                   const float* __restrict__ g20, const float* __restrict__ b20,
                                                   const float* __restrict__ g21, const float* __restrict__ b21,
                                                   const float* __restrict__ g22, const float* __restrict__ b22,
                                                   const float* __restrict__ st0, const float* __restrict__ st1,
                                                   const float* __restrict__ st2,
                                                   bf16* __restrict__ Abig, float* __restrict__ biasb) {
    __shared__ float s_sc[384], s_bc[384], s_part[256];
    int b = blockIdx.x, tid = threadIdx.x;
    for (int o = tid; o < 384; o += 256) {
        int k = o >> 7, cc = o & 127, g = cc >> 4;
        const float* st = (k == 0) ? st0 : (k == 1) ? st1 : st2;
        const float* gg = (k == 0) ? g20 : (k == 1) ? g21 : g22;
        const float* b2 = (k == 0) ? b20 : (k == 1) ? b21 : b22;
        float mu = st[b * 8 + g], rs = st[256 + b * 8 + g];
        float sc = rs * gg[cc];
        s_sc[o] = sc;
        s_bc[o] = b2[cc] - mu * sc;
    }
    __syncthreads();
    for (int o = tid; o < 128 * 448; o += 256) {
        int co = o / 448, j = o - co * 448;
        float val = (j < 384) ? fus_w[co * 384 + j] * s_sc[j] : res_w[co * 64 + (j - 384)];
        Abig[((long long)(b * 128 + co)) * 448 + j] = (bf16)val;
    }
    int co = tid & 127, half = tid >> 7;
    float part = 0.f;
    for (int jj = 0; jj < 192; ++jj) {
        int j = half * 192 + jj;
        part += fus_w[co * 384 + j] * s_bc[j];
    }
    s_part[tid] = part;
    __syncthreads();
    if (half == 0)
        biasb[b * 128 + co] = fus_b[co] + res_b[co] + s_part[co] + s_part[128 + co];
}

// ---------------- fused output GEMM: acc(fp32) = Abig @ [y3|y5|y7|xt] + bias ----------------
__global__ __launch_bounds__(256) void fuse_mfma_kernel(const bf16* __restrict__ y0, const bf16* __restrict__ y1,
                                                        const bf16* __restrict__ y2, const bf16* __restrict__ xt,
                                                        const bf16* __restrict__ Abig, const float* __restrict__ biasb,
                                                        float* __restrict__ accf) {
    __shared__ __align__(16) bf16 s_b[64 * 448];   // B operand; reused as fp32 out-stage after MFMA
    int tile = blockIdx.x, b = blockIdx.y, tid = threadIdx.x;
    int n0 = tile * 64;

    int c = tid % 56;
    int roff = tid / 56;
    bool act = tid < 224;
    const bf16* src;
    int stride;
    if (c < 48) {
        src = (c < 16 ? y0 : (c < 32 ? y1 : y2)) + (c & 15) * 8;
        stride = 128;
    } else {
        src = xt + (c - 48) * 8;
        stride = 64;
    }
    src += (long long)(b * NTV + n0) * stride;
    if (act) {
#pragma unroll
        for (int it = 0; it < 16; ++it) {
            int r = it * 4 + roff;
            uint4 v = *reinterpret_cast<const uint4*>(src + (long long)r * stride);
            *reinterpret_cast<uint4*>(s_b + r * 448 + (c ^ (r & 7)) * 8) = v;
        }
    }
    __syncthreads();

    int wid = tid >> 6, lane = tid & 63, l15 = lane & 15, l4 = lane >> 4;
    int co0 = wid * 32;
    f32x4 acc[2][4];
#pragma unroll
    for (int m = 0; m < 2; ++m)
#pragma unroll
        for (int ns = 0; ns < 4; ++ns) acc[m][ns] = f32x4{0.f, 0.f, 0.f, 0.f};

    const bf16* abase = Abig + ((long long)(b * 128 + co0 + l15)) * 448 + l4 * 8;
#pragma unroll
    for (int ks = 0; ks < 14; ++ks) {
        bf16x8 a0 = *(const bf16x8*)(abase + ks * 32);
        bf16x8 a1 = *(const bf16x8*)(abase + 16 * 448 + ks * 32);
        int ci = ks * 4 + l4;
#pragma unroll
        for (int ns = 0; ns < 4; ++ns) {
            int r = ns * 16 + l15;
            bf16x8 bv = *(const bf16x8*)(s_b + r * 448 + (ci ^ (r & 7)) * 8);
            acc[0][ns] = __builtin_amdgcn_mfma_f32_16x16x32_bf16(a0, bv, acc[0][ns], 0, 0, 0);
            acc[1][ns] = __builtin_amdgcn_mfma_f32_16x16x32_bf16(a1, bv, acc[1][ns], 0, 0, 0);
        }
    }

    float bias[2][4];
#pragma unroll
    for (int m = 0; m < 2; ++m)
#pragma unroll
        for (int rr = 0; rr < 4; ++rr) bias[m][rr] = biasb[b * 128 + co0 + m * 16 + l4 * 4 + rr];

    __syncthreads();   // all B reads complete; reuse s_b as fp32 staging
    float* s_yf = reinterpret_cast<float*>(s_b);   // [64][136] floats = 34.8 KB < 57.3 KB
#pragma unroll
    for (int m = 0; m < 2; ++m)
#pragma unroll
        for (int ns = 0; ns < 4; ++ns) {
            int nl = ns * 16 + l15;
            float4 val;
            val.x = acc[m][ns][0] + bias[m][0];
            val.y = acc[m][ns][1] + bias[m][1];
            val.z = acc[m][ns][2] + bias[m][2];
            val.w = acc[m][ns][3] + bias[m][3];
            *reinterpret_cast<float4*>(s_yf + nl * 136 + co0 + m * 16 + l4 * 4) = val;
        }
    __syncthreads();
#pragma unroll
    for (int it = 0; it < 8; ++it) {
        int flat = it * 256 + tid;
        int nl = flat >> 5, cq = flat & 31;
        float4 v = *reinterpret_cast<const float4*>(s_yf + nl * 136 + cq * 4);
        *reinterpret_cast<float4*>(accf + ((long long)(b * NTV + n0 + nl)) * 128 + cq * 4) = v;
    }
}

// ---------------- final: out = gn3(relu(acc fp32)), transpose to [b][c][n] fp32 ----------------
__global__ __launch_bounds__(256) void final_kernel(const float* __restrict__ accf,
                                                    const float* __restrict__ stats3,
                                                    const float* __restrict__ ng,
                                                    const float* __restrict__ nb,
                                                    float* __restrict__ out) {
    __shared__ float s_o[128 * 72];
    __shared__ float s_sc[128], s_bc[128];
    int tile = blockIdx.x, b = blockIdx.y, tid = threadIdx.x;
    int n0 = tile * 64;
    if (tid < 128) {
        int g = tid >> 4;
        float mu = stats3[b * 8 + g], rs = stats3[256 + b * 8 + g];
        float sv = rs * ng[tid];
        s_sc[tid] = sv;
        s_bc[tid] = nb[tid] - mu * sv;
    }
    __syncthreads();
#pragma unroll
    for (int it = 0; it < 8; ++it) {
        int flat = it * 256 + tid;
        int r = flat >> 5, cq = flat & 31;
        float4 v = *reinterpret_cast<const float4*>(accf + ((long long)(b * NTV + n0 + r)) * 128 + cq * 4);
        float f[4] = {v.x, v.y, v.z, v.w};
#pragma unroll
        for (int p = 0; p < 4; ++p) {
            int ci = cq * 4 + p;
            s_o[ci * 72 + r] = fmaxf(f[p], 0.f) * s_sc[ci] + s_bc[ci];
        }
    }
    __syncthreads();
#pragma unroll
    for (int it = 0; it < 8; ++it) {
        int flat = it * 256 + tid;
        int ci = flat >> 4, q = flat & 15;
        float4 v = *reinterpret_cast<const float4*>(s_o + ci * 72 + q * 4);
        *reinterpret_cast<float4*>(out + ((long long)(b * 128 + ci)) * NTV + n0 + q * 4) = v;
    }
}

extern "C" void kernel_launch(void* const* d_in, const int* in_sizes, int n_in,
                              void* d_out, int out_size, void* d_ws, size_t ws_size,
                              hipStream_t stream) {
    const float* x      = (const float*)d_in[0];
    const float* adj    = (const float*)d_in[1];
    const float* w_gat  = (const float*)d_in[2];
    const float* a_gat  = (const float*)d_in[3];
    const float* fus_w  = (const float*)d_in[4];
    const float* fus_b  = (const float*)d_in[5];
    const float* res_w  = (const float*)d_in[6];
    const float* res_b  = (const float*)d_in[7];
    const float* norm_g = (const float*)d_in[8];
    const float* norm_b = (const float*)d_in[9];
    const float* tg1[3], *tb1[3], *tw[3], *tbb[3], *tg2[3], *tb2[3];
    for (int i = 0; i < 3; i++) {
        tg1[i] = (const float*)d_in[10 + 6 * i + 0];
        tb1[i] = (const float*)d_in[10 + 6 * i + 1];
        tw[i]  = (const float*)d_in[10 + 6 * i + 2];
        tbb[i] = (const float*)d_in[10 + 6 * i + 3];
        tg2[i] = (const float*)d_in[10 + 6 * i + 4];
        tb2[i] = (const float*)d_in[10 + 6 * i + 5];
    }

    float* ws = (float*)d_ws;
    float* accf  = ws + ACC_OFF;                    // fp32, aliases xgt/wrb/wgr (dead by fuse)
    bf16* xgt    = (bf16*)(ws + XGT_OFF);
    bf16* wrb[3] = { (bf16*)(ws + WRB3_OFF), (bf16*)(ws + WRB5_OFF), (bf16*)(ws + WRB7_OFF) };
    float* wgr   = ws + WGR_OFF;
    bf16* yb[3]  = { (bf16*)(ws + Y0_OFF), (bf16*)(ws + Y1_OFF), (bf16*)(ws + Y2_OFF) };
    bf16* xt     = (bf16*)(ws + XT_OFF);
    bf16* Abig   = (bf16*)(ws + ABIG_OFF);
    float* biasb = ws + BIAS_OFF;
    float* S1    = ws + STATS_OFF;
    float* S2    = S1 + 512;      // 3 consecutive buffers
    float* S3    = S1 + 2048;

    const int Ks[3] = { 3, 5, 7 };

    zero_stats_kernel<<<1, 256, 0, stream>>>(S1);
    for (int i = 0; i < 3; i++) {
        int tot = 128 * 128 * Ks[i];
        repack_wbf16_kernel<<<(tot + 255) / 256, 256, 0, stream>>>(tw[i], wrb[i], Ks[i]);
    }
    repack_wg_kernel<<<32, 256, 0, stream>>>(w_gat, wgr);

    dim3 g64(100, 32), g128(50, 32), gstat(32, 16);

    xt_kernel<<<g64, 256, 0, stream>>>(x, xt);
    gat_kernel<<<B_ * T_, 256, 0, stream>>>(x, adj, wgr, a_gat, xgt);

    stats_c128_kernel<false><<<gstat, 256, 0, stream>>>(xgt, S1);
    finalize_kernel<<<1, 256, 0, stream>>>(S1);

    conv_mfma_kernel<3><<<g128, 256, 0, stream>>>(xgt, wrb[0], tbb[0], tg1[0], tb1[0], S1, yb[0]);
    conv_mfma_kernel<5><<<g128, 256, 0, stream>>>(xgt, wrb[1], tbb[1], tg1[1], tb1[1], S1, yb[1]);
    conv_mfma_kernel<7><<<g128, 256, 0, stream>>>(xgt, wrb[2], tbb[2], tg1[2], tb1[2], S1, yb[2]);

    stats_c128_kernel<false><<<gstat, 256, 0, stream>>>(yb[0], S2);
    stats_c128_kernel<false><<<gstat, 256, 0, stream>>>(yb[1], S2 + 512);
    stats_c128_kernel<false><<<gstat, 256, 0, stream>>>(yb[2], S2 + 1024);
    finalize_kernel<<<3, 256, 0, stream>>>(S2);

    fold_kernel<<<32, 256, 0, stream>>>(fus_w, fus_b, res_w, res_b,
                                        tg2[0], tb2[0], tg2[1], tb2[1], tg2[2], tb2[2],
                                        S2, S2 + 512, S2 + 1024, Abig, biasb);

    // fuse overwrites the xgt/wrb/wgr region with fp32 acc (those are dead now)
    fuse_mfma_kernel<<<g64, 256, 0, stream>>>(yb[0], yb[1], yb[2], xt, Abig, biasb, accf);

    stats_f32_relu_kernel<<<gstat, 256, 0, stream>>>(accf, S3);
    finalize_kernel<<<1, 256, 0, stream>>>(S3);

    final_kernel<<<g64, 256, 0, stream>>>(accf, S3, norm_g, norm_b, (float*)d_out);
}